// Round 6
// baseline (101.744 us; speedup 1.0000x reference)
//
#include <hip/hip_runtime.h>

// HTSK fuzzy-TSK pipeline for MI355X (gfx950), round 6.
// Theory: harness's 268MB ws-poison drain saturates HBM while our kernels run;
// remedy = latency tolerance via occupancy (16 waves/CU in both hot kernels).
// prep: build f16 MFMA B-fragments for W, W0, split-f16 logits B + kvec (validated R2).
// k1  : 1024 blocks x 16 rows: logits MFMA + softmax -> frs fp32; out := bias.
// k2  : 1024 blocks = 128 row-blocks x 8 rule-groups(16): GEMM, atomicAdd out.
// d_out = [out fp32 16384*32][frs fp32 16384*128]

#define H_CONST 0.5f
#define EPS_CONST 1e-8f
#define NROWS 16384
#define NRULES 128
#define WCOLS 8320

typedef _Float16 half8 __attribute__((ext_vector_type(8)));
typedef _Float16 half4 __attribute__((ext_vector_type(4)));
typedef float floatx4 __attribute__((ext_vector_type(4)));

#define MFMA16(a, b, c) __builtin_amdgcn_mfma_f32_16x16x32_f16((a), (b), (c), 0, 0, 0)

// ws layout (halves) — validated layout:
//   Wfrag : [r 128][s 2][nt 2][L 64][j 8]  = 262144 halves
//   W0frag: [s 4][nt 2][L 64][j 8]         =   4096 halves
//   Bmat  : [s 12][nt 8][L 64][j 8]        =  49152 halves
//   Kvec  : fp32[128] at byte offset 630784
#define WFRAG_OFF 0
#define W0FRAG_OFF 262144
#define BMAT_OFF   (262144 + 4096)
#define KVEC_BYTE_OFF 630784
#define WS_BYTES_NEEDED (630784 + 512)

// ---------------------------------------------------------------------------
// prep: 137 blocks x 256 (exact R2-validated kernel, kvec tail included).
// ---------------------------------------------------------------------------
__global__ __launch_bounds__(256) void prep_kernel(
    const float* __restrict__ centers, const float* __restrict__ sigmas,
    const float* __restrict__ W, _Float16* __restrict__ wsh, float* __restrict__ kvec)
{
    __shared__ float sBuf[32 * 68];
    const int t = threadIdx.x;
    const int b = blockIdx.x;

    if (b < 128) {
        const int r = b;
        {
            int o = t >> 3, seg = t & 7;
            const float* g = W + o * WCOLS + r * 64 + seg * 8;
            floatx4 a = *(const floatx4*)g;
            floatx4 c = *(const floatx4*)(g + 4);
            *(floatx4*)(sBuf + o * 68 + seg * 8) = a;
            *(floatx4*)(sBuf + o * 68 + seg * 8 + 4) = c;
        }
        __syncthreads();
        {
            int L = t & 63, nt = (t >> 6) & 1, s = t >> 7;
            int o = nt * 16 + (L & 15);
            int ib = s * 32 + ((L >> 4) & 3) * 8;
            floatx4 fa = *(const floatx4*)(sBuf + o * 68 + ib);
            floatx4 fb = *(const floatx4*)(sBuf + o * 68 + ib + 4);
            half8 h;
#pragma unroll
            for (int k = 0; k < 8; ++k) h[k] = (_Float16)((k < 4) ? fa[k & 3] : fb[k & 3]);
            *(half8*)(wsh + WFRAG_OFF + r * 2048 + t * 8) = h;
        }
    } else if (b < 136) {
        const int nt = b - 128;
        float* sS = sBuf;
        float* sC = sBuf + 1088;
        {
            int i = t >> 2, c0 = (t & 3) * 4;
            floatx4 sg4 = *(const floatx4*)(sigmas + i * NRULES + nt * 16 + c0);
            floatx4 ct4 = *(const floatx4*)(centers + i * NRULES + nt * 16 + c0);
#pragma unroll
            for (int k = 0; k < 4; ++k) { sS[i * 17 + c0 + k] = sg4[k]; sC[i * 17 + c0 + k] = ct4[k]; }
        }
        __syncthreads();
#pragma unroll
        for (int kk = 0; kk < 3; ++kk) {
            int unit = t + kk * 256;
            int s = unit >> 6, L = unit & 63;
            int q = (L >> 4) & 3, nl = L & 15;
            int g = s >> 1;
            int i0 = (s & 1) * 32 + q * 8;
            half8 h;
#pragma unroll
            for (int j = 0; j < 8; ++j) {
                int i = i0 + j;
                float sg = sS[i * 17 + nl];
                float S = H_CONST / (sg * sg) + EPS_CONST;
                float c = sC[i * 17 + nl];
                float CS2 = 2.0f * c * S;
                _Float16 v;
                if (g == 0 || g == 2) v = -(_Float16)S;
                else if (g == 1) { _Float16 sh = (_Float16)S; v = -(_Float16)(S - (float)sh); }
                else if (g == 3 || g == 5) v = (_Float16)CS2;
                else { _Float16 ch = (_Float16)CS2; v = (_Float16)(CS2 - (float)ch); }
                h[j] = v;
            }
            *(half8*)(wsh + BMAT_OFF + ((s * 8 + nt) * 64 + L) * 8) = h;
        }
    } else {
#pragma unroll
        for (int kk = 0; kk < 2; ++kk) {
            int unit = t + kk * 256;
            int s = unit >> 7, nt = (unit >> 6) & 1, L = unit & 63;
            int q = (L >> 4) & 3;
            int o = nt * 16 + (L & 15);
            half8 h;
#pragma unroll
            for (int j = 0; j < 8; ++j) {
                int r = s * 32 + q * 8 + j;
                h[j] = (_Float16)W[o * WCOLS + 8192 + r];
            }
            *(half8*)(wsh + W0FRAG_OFF + ((s * 2 + nt) * 64 + L) * 8) = h;
        }
        if (t < 128) {
            int r = t;
            float acc = 0.f;
#pragma unroll 8
            for (int i = 0; i < 64; ++i) {
                float sg = sigmas[i * NRULES + r];
                float S = H_CONST / (sg * sg) + EPS_CONST;
                float c = centers[i * NRULES + r];
                acc += c * c * S;
            }
            kvec[r] = acc;
        }
    }
}

// ---------------------------------------------------------------------------
// k1: 1024 blocks x 256, 16 rows/block (16 waves/CU). logits + softmax ->
//     frs fp32; out := bias.  LDS = 4*2KB + 8448B = 16.6KB.
// ---------------------------------------------------------------------------
__global__ __launch_bounds__(256) void k1_frs(
    const float* __restrict__ X, const float* __restrict__ bias,
    const _Float16* __restrict__ wsh, const float* __restrict__ kvec,
    float* __restrict__ out, float* __restrict__ frs_out)
{
    __shared__ _Float16 sXh[16 * 64];
    __shared__ _Float16 sXl[16 * 64];
    __shared__ _Float16 sX2h[16 * 64];
    __shared__ _Float16 sX2l[16 * 64];
    __shared__ float sU[16 * 132];

    const int t = threadIdx.x;
    const int w = t >> 6;
    const int L = t & 63;
    const int m = L & 15;
    const int q = L >> 4;
    const int row0 = blockIdx.x * 16;

    // ---- A: stage X splits. 128 units of 8 halves; 2 threads per unit ----
    {
        int u = t >> 1, hs = t & 1;        // u 0..127
        int row = u >> 3, uc = u & 7;
        const float* gx = X + (row0 + row) * 64 + uc * 8 + hs * 4;
        floatx4 xa = *(const floatx4*)gx;
        int base = row * 64 + (uc ^ (row & 7)) * 8 + hs * 4;
        half4 vh, vl, v2h, v2l;
#pragma unroll
        for (int k = 0; k < 4; ++k) {
            float x = xa[k];
            _Float16 xh = (_Float16)x;
            _Float16 xl2 = (_Float16)(x - (float)xh);
            float x2 = x * x;
            _Float16 x2h = (_Float16)x2;
            _Float16 x2l = (_Float16)(x2 - (float)x2h);
            vh[k] = xh; vl[k] = xl2; v2h[k] = x2h; v2l[k] = x2l;
        }
        *(half4*)(sXh + base) = vh;
        *(half4*)(sXl + base) = vl;
        *(half4*)(sX2h + base) = v2h;
        *(half4*)(sX2l + base) = v2l;
    }
    __syncthreads();

    // ---- B: logits MFMA; wave w -> rule n-tiles {2w,2w+1}, single m-tile ----
    floatx4 lacc0 = (floatx4){0.f, 0.f, 0.f, 0.f};
    floatx4 lacc1 = (floatx4){0.f, 0.f, 0.f, 0.f};

    const _Float16* Bm = wsh + BMAT_OFF;
#pragma unroll
    for (int s = 0; s < 12; ++s) {
        const _Float16* arr = (s < 4) ? sX2h : (s < 6) ? sX2l : (s < 10) ? sXh : sXl;
        int phys = (((s & 1) << 2) | q) ^ (m & 7);
        half8 b0 = *(const half8*)(Bm + ((s * 8 + 2 * w + 0) * 64 + L) * 8);
        half8 b1 = *(const half8*)(Bm + ((s * 8 + 2 * w + 1) * 64 + L) * 8);
        half8 a = *(const half8*)(arr + m * 64 + phys * 8);
        lacc0 = MFMA16(a, b0, lacc0);
        lacc1 = MFMA16(a, b1, lacc1);
    }
    float kv0 = kvec[(2 * w + 0) * 16 + m];
    float kv1 = kvec[(2 * w + 1) * 16 + m];

#pragma unroll
    for (int reg = 0; reg < 4; ++reg) {
        int rl = q * 4 + reg;                       // 0..15
        sU[rl * 132 + (2 * w + 0) * 16 + m] = lacc0[reg] - kv0;
        sU[rl * 132 + (2 * w + 1) * 16 + m] = lacc1[reg] - kv1;
    }
    __syncthreads();

    // ---- C: softmax, 16 threads/row x 8 cols ----
    {
        int row = t >> 4, l16 = t & 15;
        int base = row * 132 + l16 * 8;
        float v[8];
        float mx = -1e30f;
#pragma unroll
        for (int k = 0; k < 8; ++k) { v[k] = sU[base + k]; mx = fmaxf(mx, v[k]); }
        mx = fmaxf(mx, __shfl_xor(mx, 1));
        mx = fmaxf(mx, __shfl_xor(mx, 2));
        mx = fmaxf(mx, __shfl_xor(mx, 4));
        mx = fmaxf(mx, __shfl_xor(mx, 8));
        float sum = 0.f;
#pragma unroll
        for (int k = 0; k < 8; ++k) { v[k] = __expf(v[k] - mx); sum += v[k]; }
        sum += __shfl_xor(sum, 1);
        sum += __shfl_xor(sum, 2);
        sum += __shfl_xor(sum, 4);
        sum += __shfl_xor(sum, 8);
        float inv = 1.0f / sum;
        float* gf = frs_out + (row0 + row) * 128 + l16 * 8;
        floatx4 f0, f1;
#pragma unroll
        for (int k = 0; k < 4; ++k) { f0[k] = v[k] * inv; f1[k] = v[k + 4] * inv; }
        *(floatx4*)gf = f0;
        *(floatx4*)(gf + 4) = f1;
    }

    // ---- out := bias (atomics target) ----
    if (t < 128) {
        int row = t >> 3, c0 = (t & 7) * 4;
        floatx4 b4 = *(const floatx4*)(bias + c0);
        *(floatx4*)(out + (row0 + row) * 32 + c0) = b4;
    }
}

// ---------------------------------------------------------------------------
// k2: 1024 blocks x 256 = 128 row-blocks (128 rows) x 8 rule-groups (16).
//     16 waves/CU; per-block Wfrag slice 64KB; atomicAdd epilogue.
// ---------------------------------------------------------------------------
__global__ __launch_bounds__(256) void k2_gemm(
    const float* __restrict__ X, const float* __restrict__ frs32,
    const _Float16* __restrict__ wsh, float* __restrict__ out)
{
    __shared__ _Float16 sXf[128 * 64];  // 16 KB
    __shared__ _Float16 sF[128 * 18];   // 4.5 KB, pad stride 18

    const int t = threadIdx.x;
    const int w = t >> 6;
    const int L = t & 63;
    const int m = L & 15;
    const int q = L >> 4;
    const int rb = blockIdx.x >> 3;
    const int g = blockIdx.x & 7;
    const int row0 = rb * 128;

    // stage X (f16, swizzled) + frs group slice (f16)
    {
        int row = t >> 1, hf = t & 1;
        const float* gx = X + (row0 + row) * 64 + hf * 32;
#pragma unroll
        for (int c = 0; c < 4; ++c) {
            int uc = hf * 4 + c;
            floatx4 a = *(const floatx4*)(gx + c * 8);
            floatx4 bb = *(const floatx4*)(gx + c * 8 + 4);
            half8 h;
#pragma unroll
            for (int k = 0; k < 8; ++k) h[k] = (_Float16)((k < 4) ? a[k & 3] : bb[k & 3]);
            *(half8*)(sXf + row * 64 + (uc ^ (row & 7)) * 8) = h;
        }
        const float* gfr = frs32 + (row0 + row) * 128 + g * 16 + hf * 8;
        floatx4 a = *(const floatx4*)gfr;
        floatx4 bb = *(const floatx4*)(gfr + 4);
        half8 h;
#pragma unroll
        for (int k = 0; k < 8; ++k) h[k] = (_Float16)((k < 4) ? a[k & 3] : bb[k & 3]);
        *(half8*)(sF + row * 18 + hf * 8) = h;
    }
    __syncthreads();

    // wave w owns m-tiles {2w, 2w+1}
    const int r0w0 = (2 * w + 0) * 16 + m;
    const int r0w1 = (2 * w + 1) * 16 + m;

    half8 xf[2][2];
#pragma unroll
    for (int mtl = 0; mtl < 2; ++mtl) {
        int mt = 2 * w + mtl;
#pragma unroll
        for (int s = 0; s < 2; ++s) {
            int phys = ((s << 2) | q) ^ (m & 7);
            xf[mtl][s] = *(const half8*)(sXf + (mt * 16 + m) * 64 + phys * 8);
        }
    }

    half8 fvA0 = *(const half8*)(sF + r0w0 * 18);
    half8 fvB0 = *(const half8*)(sF + r0w0 * 18 + 8);
    half8 fvA1 = *(const half8*)(sF + r0w1 * 18);
    half8 fvB1 = *(const half8*)(sF + r0w1 * 18 + 8);

    floatx4 oacc[2][2];
#pragma unroll
    for (int mtl = 0; mtl < 2; ++mtl)
#pragma unroll
        for (int n = 0; n < 2; ++n) oacc[mtl][n] = (floatx4){0.f, 0.f, 0.f, 0.f};

    const _Float16* Wf = wsh + WFRAG_OFF;
    const _Float16* W0f = wsh + W0FRAG_OFF;

#define LDW(r, slot) (*(const half8*)(Wf + (r) * 2048 + ((slot) * 64 + L) * 8))

    half8 b00 = LDW(g * 16, 0), b01 = LDW(g * 16, 1);
    half8 b10 = LDW(g * 16, 2), b11 = LDW(g * 16, 3);

#pragma unroll
    for (int rr = 0; rr < 16; ++rr) {
        half8 c00 = b00, c01 = b01, c10 = b10, c11 = b11;
        if (rr < 15) {
            int rn = g * 16 + rr + 1;
            b00 = LDW(rn, 0); b01 = LDW(rn, 1); b10 = LDW(rn, 2); b11 = LDW(rn, 3);
        }
        _Float16 f0 = (rr < 8) ? fvA0[rr & 7] : fvB0[rr & 7];
        _Float16 f1 = (rr < 8) ? fvA1[rr & 7] : fvB1[rr & 7];
        half8 fs0, fs1;
#pragma unroll
        for (int k = 0; k < 8; ++k) { fs0[k] = f0; fs1[k] = f1; }
        half8 a00 = fs0 * xf[0][0];
        half8 a01 = fs0 * xf[0][1];
        half8 a10 = fs1 * xf[1][0];
        half8 a11 = fs1 * xf[1][1];
        oacc[0][0] = MFMA16(a00, c00, oacc[0][0]);
        oacc[0][0] = MFMA16(a01, c10, oacc[0][0]);
        oacc[0][1] = MFMA16(a00, c01, oacc[0][1]);
        oacc[0][1] = MFMA16(a01, c11, oacc[0][1]);
        oacc[1][0] = MFMA16(a10, c00, oacc[1][0]);
        oacc[1][0] = MFMA16(a11, c10, oacc[1][0]);
        oacc[1][1] = MFMA16(a10, c01, oacc[1][1]);
        oacc[1][1] = MFMA16(a11, c11, oacc[1][1]);
    }

    // W0 term: group g = rules g*16..g*16+15, chunk s=g>>1, k-range (g&1)*16..+15.
    // Lane contributes iff its q covers that k-range; A holds frs at k=q*8+j.
    {
        int s = g >> 1;
        bool valid = ((q >> 1) == (g & 1));
        half8 zero;
#pragma unroll
        for (int k = 0; k < 8; ++k) zero[k] = (_Float16)0.f;
        half8 wb0 = *(const half8*)(W0f + ((s * 2 + 0) * 64 + L) * 8);
        half8 wb1 = *(const half8*)(W0f + ((s * 2 + 1) * 64 + L) * 8);
        half8 a0 = valid ? *(const half8*)(sF + r0w0 * 18 + (q & 1) * 8) : zero;
        half8 a1 = valid ? *(const half8*)(sF + r0w1 * 18 + (q & 1) * 8) : zero;
        oacc[0][0] = MFMA16(a0, wb0, oacc[0][0]);
        oacc[0][1] = MFMA16(a0, wb1, oacc[0][1]);
        oacc[1][0] = MFMA16(a1, wb0, oacc[1][0]);
        oacc[1][1] = MFMA16(a1, wb1, oacc[1][1]);
    }

    // epilogue: atomic accumulate (device-scope fp32; R2 measured ~free)
#pragma unroll
    for (int mtl = 0; mtl < 2; ++mtl)
#pragma unroll
        for (int ntl = 0; ntl < 2; ++ntl)
#pragma unroll
            for (int reg = 0; reg < 4; ++reg) {
                int rowo = (2 * w + mtl) * 16 + q * 4 + reg;
                int colo = ntl * 16 + m;
                atomicAdd(out + (row0 + rowo) * 32 + colo, oacc[mtl][ntl][reg]);
            }
#undef LDW
}

extern "C" void kernel_launch(void* const* d_in, const int* in_sizes, int n_in,
                              void* d_out, int out_size, void* d_ws, size_t ws_size,
                              hipStream_t stream) {
    const float* X = (const float*)d_in[0];
    const float* centers = (const float*)d_in[1];
    const float* sigmas = (const float*)d_in[2];
    const float* W = (const float*)d_in[3];
    const float* b = (const float*)d_in[4];
    float* outp = (float*)d_out;               // [16384*32]
    float* frs_out = outp + NROWS * 32;        // [16384*128]
    if (ws_size < (size_t)WS_BYTES_NEEDED) return;
    _Float16* wsh = (_Float16*)d_ws;
    float* kvec = (float*)((char*)d_ws + KVEC_BYTE_OFF);

    prep_kernel<<<137, 256, 0, stream>>>(centers, sigmas, W, wsh, kvec);
    k1_frs<<<NROWS / 16, 256, 0, stream>>>(X, b, wsh, kvec, outp, frs_out);
    k2_gemm<<<(NROWS / 128) * 8, 256, 0, stream>>>(X, frs_out, wsh, outp);
}

// Round 7
// 84.807 us; speedup vs baseline: 1.1997x; 1.1997x over previous
//
#include <hip/hip_runtime.h>

// HTSK fuzzy-TSK fused pipeline for MI355X (gfx950), round 7.
// Theory: kernel time is dominated by exposed L2/LLC latency in the B/D loops
// (depth-1 prefetch, 2 waves/SIMD). Fix: bulk-issue B-fragment loads up front
// (B-loop = pure LDS+MFMA) and a depth-4 register ring in D (16 loads in
// flight, compiler emits vmcnt(N>0) waits — AITER pattern).
// prep: R2-validated fragment builder (kvec folded back in).
// d_out = [out fp32 16384*32][frs fp32 16384*128]

#define H_CONST 0.5f
#define EPS_CONST 1e-8f
#define NROWS 16384
#define NRULES 128
#define WCOLS 8320

typedef _Float16 half8 __attribute__((ext_vector_type(8)));
typedef float floatx4 __attribute__((ext_vector_type(4)));

#define MFMA16(a, b, c) __builtin_amdgcn_mfma_f32_16x16x32_f16((a), (b), (c), 0, 0, 0)

// ws layout (halves) — validated:
//   Wfrag : [r 128][s 2][nt 2][L 64][j 8]  = 262144 halves
//   W0frag: [s 4][nt 2][L 64][j 8]         =   4096 halves
//   Bmat  : [s 12][nt 8][L 64][j 8]        =  49152 halves
//   Kvec  : fp32[128] at byte offset 630784
#define WFRAG_OFF 0
#define W0FRAG_OFF 262144
#define BMAT_OFF   (262144 + 4096)
#define KVEC_BYTE_OFF 630784
#define WS_BYTES_NEEDED (630784 + 512)

// ---------------------------------------------------------------------------
// prep: 137 blocks x 256 (exact R2-validated kernel).
// ---------------------------------------------------------------------------
__global__ __launch_bounds__(256) void prep_kernel(
    const float* __restrict__ centers, const float* __restrict__ sigmas,
    const float* __restrict__ W, _Float16* __restrict__ wsh, float* __restrict__ kvec)
{
    __shared__ float sBuf[32 * 68];
    const int t = threadIdx.x;
    const int b = blockIdx.x;

    if (b < 128) {
        const int r = b;
        {
            int o = t >> 3, seg = t & 7;
            const float* g = W + o * WCOLS + r * 64 + seg * 8;
            floatx4 a = *(const floatx4*)g;
            floatx4 c = *(const floatx4*)(g + 4);
            *(floatx4*)(sBuf + o * 68 + seg * 8) = a;
            *(floatx4*)(sBuf + o * 68 + seg * 8 + 4) = c;
        }
        __syncthreads();
        {
            int L = t & 63, nt = (t >> 6) & 1, s = t >> 7;
            int o = nt * 16 + (L & 15);
            int ib = s * 32 + ((L >> 4) & 3) * 8;
            floatx4 fa = *(const floatx4*)(sBuf + o * 68 + ib);
            floatx4 fb = *(const floatx4*)(sBuf + o * 68 + ib + 4);
            half8 h;
#pragma unroll
            for (int k = 0; k < 8; ++k) h[k] = (_Float16)((k < 4) ? fa[k & 3] : fb[k & 3]);
            *(half8*)(wsh + WFRAG_OFF + r * 2048 + t * 8) = h;
        }
    } else if (b < 136) {
        const int nt = b - 128;
        float* sS = sBuf;
        float* sC = sBuf + 1088;
        {
            int i = t >> 2, c0 = (t & 3) * 4;
            floatx4 sg4 = *(const floatx4*)(sigmas + i * NRULES + nt * 16 + c0);
            floatx4 ct4 = *(const floatx4*)(centers + i * NRULES + nt * 16 + c0);
#pragma unroll
            for (int k = 0; k < 4; ++k) { sS[i * 17 + c0 + k] = sg4[k]; sC[i * 17 + c0 + k] = ct4[k]; }
        }
        __syncthreads();
#pragma unroll
        for (int kk = 0; kk < 3; ++kk) {
            int unit = t + kk * 256;
            int s = unit >> 6, L = unit & 63;
            int q = (L >> 4) & 3, nl = L & 15;
            int g = s >> 1;
            int i0 = (s & 1) * 32 + q * 8;
            half8 h;
#pragma unroll
            for (int j = 0; j < 8; ++j) {
                int i = i0 + j;
                float sg = sS[i * 17 + nl];
                float S = H_CONST / (sg * sg) + EPS_CONST;
                float c = sC[i * 17 + nl];
                float CS2 = 2.0f * c * S;
                _Float16 v;
                if (g == 0 || g == 2) v = -(_Float16)S;
                else if (g == 1) { _Float16 sh = (_Float16)S; v = -(_Float16)(S - (float)sh); }
                else if (g == 3 || g == 5) v = (_Float16)CS2;
                else { _Float16 ch = (_Float16)CS2; v = (_Float16)(CS2 - (float)ch); }
                h[j] = v;
            }
            *(half8*)(wsh + BMAT_OFF + ((s * 8 + nt) * 64 + L) * 8) = h;
        }
    } else {
#pragma unroll
        for (int kk = 0; kk < 2; ++kk) {
            int unit = t + kk * 256;
            int s = unit >> 7, nt = (unit >> 6) & 1, L = unit & 63;
            int q = (L >> 4) & 3;
            int o = nt * 16 + (L & 15);
            half8 h;
#pragma unroll
            for (int j = 0; j < 8; ++j) {
                int r = s * 32 + q * 8 + j;
                h[j] = (_Float16)W[o * WCOLS + 8192 + r];
            }
            *(half8*)(wsh + W0FRAG_OFF + ((s * 2 + nt) * 64 + L) * 8) = h;
        }
        if (t < 128) {
            int r = t;
            float acc = 0.f;
#pragma unroll 8
            for (int i = 0; i < 64; ++i) {
                float sg = sigmas[i * NRULES + r];
                float S = H_CONST / (sg * sg) + EPS_CONST;
                float c = centers[i * NRULES + r];
                acc += c * c * S;
            }
            kvec[r] = acc;
        }
    }
}

// ---------------------------------------------------------------------------
// main (fused): 512 blocks x 256, 32 rows/block.
//   top: issue ALL 24 Bmat loads + kvec loads (in flight through phase A)
//   A: stage X splits -> LDS
//   B: logits MFMA (pure LDS+MFMA, operands already in registers)
//   C: softmax -> frs fp32 global + frs f16 LDS (D ring fills before barrier)
//   D: GEMM, wave = rule-quarter, depth-4 register ring on Wfrag
//   E: one-barrier 4-way LDS reduce + bias + store
// ---------------------------------------------------------------------------
__global__ __launch_bounds__(256) void main_fused(
    const float* __restrict__ X, const float* __restrict__ bias,
    const _Float16* __restrict__ wsh, const float* __restrict__ kvec,
    float* __restrict__ out, float* __restrict__ frs_out)
{
    __shared__ _Float16 sXh[32 * 64];
    __shared__ _Float16 sXl[32 * 64];
    __shared__ _Float16 sX2h[32 * 64];
    __shared__ _Float16 sX2l[32 * 64];
    __shared__ _Float16 sF[32 * 136];   // frs f16, row stride 136
    __shared__ float sU[4608];          // logits (stride 132) / sP[4][32][36]

    const int t = threadIdx.x;
    const int w = t >> 6;
    const int L = t & 63;
    const int m = L & 15;
    const int q = L >> 4;
    const int row0 = blockIdx.x * 32;

    // ---- top: bulk-issue all Bmat fragment loads (24 x dwordx4) + kvec ----
    const _Float16* Bm = wsh + BMAT_OFF;
    half8 Bv[12][2];
#pragma unroll
    for (int s = 0; s < 12; ++s) {
        Bv[s][0] = *(const half8*)(Bm + ((s * 8 + 2 * w + 0) * 64 + L) * 8);
        Bv[s][1] = *(const half8*)(Bm + ((s * 8 + 2 * w + 1) * 64 + L) * 8);
    }
    float kv0 = kvec[(2 * w + 0) * 16 + m];
    float kv1 = kvec[(2 * w + 1) * 16 + m];

    // ---- A: stage X splits ----
    {
        int row = t >> 3, uc = t & 7;
        const float* gx = X + (row0 + row) * 64 + uc * 8;
        floatx4 xa = *(const floatx4*)gx;
        floatx4 xb = *(const floatx4*)(gx + 4);
        int base = row * 64 + (uc ^ (row & 7)) * 8;
        half8 vh, vl, v2h, v2l;
#pragma unroll
        for (int k = 0; k < 8; ++k) {
            float x = (k < 4) ? xa[k & 3] : xb[k & 3];
            _Float16 xh = (_Float16)x;
            _Float16 xl2 = (_Float16)(x - (float)xh);
            float x2 = x * x;
            _Float16 x2h = (_Float16)x2;
            _Float16 x2l = (_Float16)(x2 - (float)x2h);
            vh[k] = xh; vl[k] = xl2; v2h[k] = x2h; v2l[k] = x2l;
        }
        *(half8*)(sXh + base) = vh;
        *(half8*)(sXl + base) = vl;
        *(half8*)(sX2h + base) = v2h;
        *(half8*)(sX2l + base) = v2l;
    }
    __syncthreads();

    // ---- B: logits MFMA; wave w -> rule n-tiles {2w,2w+1}, m-tiles 0..1 ----
    floatx4 lacc[2][2];
#pragma unroll
    for (int mt = 0; mt < 2; ++mt)
#pragma unroll
        for (int n = 0; n < 2; ++n) lacc[mt][n] = (floatx4){0.f, 0.f, 0.f, 0.f};

#pragma unroll
    for (int s = 0; s < 12; ++s) {
        const _Float16* arr = (s < 4) ? sX2h : (s < 6) ? sX2l : (s < 10) ? sXh : sXl;
        int phys = (((s & 1) << 2) | q) ^ (m & 7);
#pragma unroll
        for (int mt = 0; mt < 2; ++mt) {
            half8 a = *(const half8*)(arr + (mt * 16 + m) * 64 + phys * 8);
            lacc[mt][0] = MFMA16(a, Bv[s][0], lacc[mt][0]);
            lacc[mt][1] = MFMA16(a, Bv[s][1], lacc[mt][1]);
        }
    }

#pragma unroll
    for (int mt = 0; mt < 2; ++mt)
#pragma unroll
        for (int ntl = 0; ntl < 2; ++ntl)
#pragma unroll
            for (int reg = 0; reg < 4; ++reg) {
                int rl = mt * 16 + q * 4 + reg;
                int col = (2 * w + ntl) * 16 + m;
                sU[rl * 132 + col] = lacc[mt][ntl][reg] - (ntl ? kv1 : kv0);
            }

    // ---- issue D's ring fill + W0 loads BEFORE the softmax barriers ----
    const int rq = w;
    const int r0 = rq * 32;
    const _Float16* Wf = wsh + WFRAG_OFF;
    const _Float16* W0f = wsh + W0FRAG_OFF;
#define LDW(r, slot) (*(const half8*)(Wf + (r) * 2048 + ((slot) * 64 + L) * 8))

    half8 ring[4][4];
#pragma unroll
    for (int p = 0; p < 4; ++p) {
        ring[p][0] = LDW(r0 + p, 0);
        ring[p][1] = LDW(r0 + p, 1);
        ring[p][2] = LDW(r0 + p, 2);
        ring[p][3] = LDW(r0 + p, 3);
    }
    half8 wb0 = *(const half8*)(W0f + ((rq * 2 + 0) * 64 + L) * 8);
    half8 wb1 = *(const half8*)(W0f + ((rq * 2 + 1) * 64 + L) * 8);

    __syncthreads();

    // ---- C: parallel softmax (8 threads/row); frs -> global fp32 + LDS f16 ----
    {
        int row = t >> 3, l8 = t & 7;
        int base = row * 132 + l8 * 16;
        float v[16];
        float mx = -1e30f;
#pragma unroll
        for (int k = 0; k < 16; ++k) { v[k] = sU[base + k]; mx = fmaxf(mx, v[k]); }
        mx = fmaxf(mx, __shfl_xor(mx, 1));
        mx = fmaxf(mx, __shfl_xor(mx, 2));
        mx = fmaxf(mx, __shfl_xor(mx, 4));
        float sum = 0.f;
#pragma unroll
        for (int k = 0; k < 16; ++k) { v[k] = __expf(v[k] - mx); sum += v[k]; }
        sum += __shfl_xor(sum, 1);
        sum += __shfl_xor(sum, 2);
        sum += __shfl_xor(sum, 4);
        float inv = 1.0f / sum;
        float* gf = frs_out + (row0 + row) * 128 + l8 * 16;
        half8 h0, h1;
#pragma unroll
        for (int c = 0; c < 4; ++c) {
            floatx4 o4;
#pragma unroll
            for (int k = 0; k < 4; ++k) {
                float f = v[c * 4 + k] * inv;
                o4[k] = f;
                if (c < 2) h0[c * 4 + k] = (_Float16)f; else h1[(c - 2) * 4 + k] = (_Float16)f;
            }
            *(floatx4*)(gf + c * 4) = o4;
        }
        *(half8*)(sF + row * 136 + l8 * 16) = h0;
        *(half8*)(sF + row * 136 + l8 * 16 + 8) = h1;
    }
    __syncthreads();

    // ---- D: GEMM, rule-quarter per wave, depth-4 ring ----
    half8 xf[2][2];
#pragma unroll
    for (int mt = 0; mt < 2; ++mt)
#pragma unroll
        for (int s = 0; s < 2; ++s) {
            int phys = ((s << 2) | q) ^ (m & 7);
            xf[mt][s] = *(const half8*)(sXh + (mt * 16 + m) * 64 + phys * 8);
        }

    floatx4 oacc[2][2];
#pragma unroll
    for (int mt = 0; mt < 2; ++mt)
#pragma unroll
        for (int n = 0; n < 2; ++n) oacc[mt][n] = (floatx4){0.f, 0.f, 0.f, 0.f};

#pragma unroll
    for (int rg = 0; rg < 4; ++rg) {
        half8 fv0 = *(const half8*)(sF + (0 * 16 + m) * 136 + r0 + rg * 8);
        half8 fv1 = *(const half8*)(sF + (1 * 16 + m) * 136 + r0 + rg * 8);
#pragma unroll
        for (int rr2 = 0; rr2 < 8; ++rr2) {
            int rr = rg * 8 + rr2;
            int slot = rr & 3;
            half8 c00 = ring[slot][0], c01 = ring[slot][1];
            half8 c10 = ring[slot][2], c11 = ring[slot][3];
            if (rr < 28) {
                int rn = r0 + rr + 4;
                ring[slot][0] = LDW(rn, 0);
                ring[slot][1] = LDW(rn, 1);
                ring[slot][2] = LDW(rn, 2);
                ring[slot][3] = LDW(rn, 3);
            }
            _Float16 f0 = fv0[rr2], f1 = fv1[rr2];
            half8 fs0, fs1;
#pragma unroll
            for (int k = 0; k < 8; ++k) { fs0[k] = f0; fs1[k] = f1; }
            half8 a00 = fs0 * xf[0][0];
            half8 a01 = fs0 * xf[0][1];
            half8 a10 = fs1 * xf[1][0];
            half8 a11 = fs1 * xf[1][1];
            oacc[0][0] = MFMA16(a00, c00, oacc[0][0]);
            oacc[0][0] = MFMA16(a01, c10, oacc[0][0]);
            oacc[0][1] = MFMA16(a00, c01, oacc[0][1]);
            oacc[0][1] = MFMA16(a01, c11, oacc[0][1]);
            oacc[1][0] = MFMA16(a10, c00, oacc[1][0]);
            oacc[1][0] = MFMA16(a11, c10, oacc[1][0]);
            oacc[1][1] = MFMA16(a10, c01, oacc[1][1]);
            oacc[1][1] = MFMA16(a11, c11, oacc[1][1]);
        }
    }

    // W0 term: this quarter's 32 rules
    {
#pragma unroll
        for (int mt = 0; mt < 2; ++mt) {
            half8 a = *(const half8*)(sF + (mt * 16 + m) * 136 + rq * 32 + q * 8);
            oacc[mt][0] = MFMA16(a, wb0, oacc[mt][0]);
            oacc[mt][1] = MFMA16(a, wb1, oacc[mt][1]);
        }
    }

#pragma unroll
    for (int mt = 0; mt < 2; ++mt)
#pragma unroll
        for (int ntl = 0; ntl < 2; ++ntl)
#pragma unroll
            for (int reg = 0; reg < 4; ++reg)
                sU[w * 1152 + (mt * 16 + q * 4 + reg) * 36 + ntl * 16 + m] = oacc[mt][ntl][reg];
    __syncthreads();

    // ---- E: 4-way reduce + bias + store ----
    {
        int row = t >> 3, col0 = (t & 7) * 4;
        floatx4 acc = *(const floatx4*)(sU + 0 * 1152 + row * 36 + col0);
        acc += *(const floatx4*)(sU + 1 * 1152 + row * 36 + col0);
        acc += *(const floatx4*)(sU + 2 * 1152 + row * 36 + col0);
        acc += *(const floatx4*)(sU + 3 * 1152 + row * 36 + col0);
        acc += *(const floatx4*)(bias + col0);
        *(floatx4*)(out + (row0 + row) * 32 + col0) = acc;
    }
#undef LDW
}

extern "C" void kernel_launch(void* const* d_in, const int* in_sizes, int n_in,
                              void* d_out, int out_size, void* d_ws, size_t ws_size,
                              hipStream_t stream) {
    const float* X = (const float*)d_in[0];
    const float* centers = (const float*)d_in[1];
    const float* sigmas = (const float*)d_in[2];
    const float* W = (const float*)d_in[3];
    const float* b = (const float*)d_in[4];
    float* outp = (float*)d_out;               // [16384*32]
    float* frs_out = outp + NROWS * 32;        // [16384*128]
    if (ws_size < (size_t)WS_BYTES_NEEDED) return;
    _Float16* wsh = (_Float16*)d_ws;
    float* kvec = (float*)((char*)d_ws + KVEC_BYTE_OFF);

    prep_kernel<<<137, 256, 0, stream>>>(centers, sigmas, W, wsh, kvec);
    main_fused<<<NROWS / 32, 256, 0, stream>>>(X, b, wsh, kvec, outp, frs_out);
}